// Round 7
// baseline (207.100 us; speedup 1.0000x reference)
//
#include <hip/hip_runtime.h>
#include <math.h>
#include <string.h>

#define EPSF 1e-6f
#define TCLIP (1.0f - 1e-5f)
#define NPTS 16384
#define DDIM 256
#define NBLK 128
#define NTHR 1024
#define PPB 128   // points per block
#define NWAVE 16
#define PPW 8     // points per wave (registers: 8 x float4 = 32 VGPRs)
#define PSTR 260  // row: 256 vec + sA@256 + wd@257 + tag@258 + pad
#define FRECHET_ITERS_N 10

// ws float layout: two partial buffers, all accesses via sc1 (coherent path)
#define WS_PA 64
#define WS_PB (WS_PA + NBLK * PSTR)

// --- coherent-path (sc1) accessors: bypass L2 both ways, no fences needed ---
__device__ __forceinline__ void st_pair_sc1(float* addr, float a, float b) {
    float2 f2 = make_float2(a, b);
    double dv; memcpy(&dv, &f2, 8);
    __hip_atomic_store((double*)addr, dv, __ATOMIC_RELAXED, __HIP_MEMORY_SCOPE_AGENT);
}
__device__ __forceinline__ float2 ld_pair_sc1(const float* addr) {
    double dv = __hip_atomic_load((const double*)addr, __ATOMIC_RELAXED, __HIP_MEMORY_SCOPE_AGENT);
    float2 f2; memcpy(&f2, &dv, 8);
    return f2;
}
__device__ __forceinline__ void st_f_sc1(float* addr, float v) {
    __hip_atomic_store(addr, v, __ATOMIC_RELAXED, __HIP_MEMORY_SCOPE_AGENT);
}
__device__ __forceinline__ void st_u_sc1(unsigned* addr, unsigned v) {
    __hip_atomic_store(addr, v, __ATOMIC_RELAXED, __HIP_MEMORY_SCOPE_AGENT);
}
__device__ __forceinline__ unsigned ld_u_sc1(const unsigned* addr) {
    return __hip_atomic_load(addr, __ATOMIC_RELAXED, __HIP_MEMORY_SCOPE_AGENT);
}

__device__ __forceinline__ float block_sum(float v) {
    __shared__ float s_bs[NWAVE];
    #pragma unroll
    for (int off = 32; off; off >>= 1) v += __shfl_xor(v, off);
    const int w = threadIdx.x >> 6, l = threadIdx.x & 63;
    __syncthreads();
    if (l == 0) s_bs[w] = v;
    __syncthreads();
    float s = 0.f;
    #pragma unroll
    for (int i = 0; i < NWAVE; ++i) s += s_bs[i];
    return s;
}

__device__ __forceinline__ void block_sum2(float& a, float& b) {
    __shared__ float sa2[NWAVE], sb2[NWAVE];
    #pragma unroll
    for (int off = 32; off; off >>= 1) { a += __shfl_xor(a, off); b += __shfl_xor(b, off); }
    const int w = threadIdx.x >> 6, l = threadIdx.x & 63;
    __syncthreads();
    if (l == 0) { sa2[w] = a; sb2[w] = b; }
    __syncthreads();
    a = 0.f; b = 0.f;
    #pragma unroll
    for (int i = 0; i < NWAVE; ++i) { a += sa2[i]; b += sb2[i]; }
}

__device__ __forceinline__ void block_sum3(float& a, float& b, float& cc) {
    __shared__ float sa3[NWAVE], sb3[NWAVE], sc3[NWAVE];
    #pragma unroll
    for (int off = 32; off; off >>= 1) {
        a += __shfl_xor(a, off); b += __shfl_xor(b, off); cc += __shfl_xor(cc, off);
    }
    const int w = threadIdx.x >> 6, l = threadIdx.x & 63;
    __syncthreads();
    if (l == 0) { sa3[w] = a; sb3[w] = b; sc3[w] = cc; }
    __syncthreads();
    a = 0.f; b = 0.f; cc = 0.f;
    #pragma unroll
    for (int i = 0; i < NWAVE; ++i) { a += sa3[i]; b += sb3[i]; cc += sc3[i]; }
}

// zero all tag slots via sc1 (ws is poisoned to 0xAA -> would read as "arrived")
__global__ void init_tags(float* ws) {
    int t = threadIdx.x;
    if (t < NBLK) {
        st_u_sc1((unsigned*)(ws + WS_PA + t * PSTR + 258), 0u);
        st_u_sc1((unsigned*)(ws + WS_PB + t * PSTR + 258), 0u);
    }
}

__global__ __launch_bounds__(NTHR, 1) void rbn_fused(
    const float* __restrict__ x, const float* __restrict__ Kp,
    const float* __restrict__ mean_param, const float* __restrict__ var_param,
    float* __restrict__ out, float* __restrict__ ws)
{
    const float c = -Kp[0];
    const float sc = sqrtf(c);
    const float N1 = 1.f / NPTS;
    const int t = threadIdx.x, lane = t & 63, wv = t >> 6;
    const int b = blockIdx.x;
    const int p0 = b * PPB;
    const float4* xr = ((const float4*)x) + p0 * 64;

    float* PA = ws + WS_PA;
    float* PB = ws + WS_PB;

    __shared__ float mu_s[DDIM], om_s[DDIM], g_s[DDIM];
    __shared__ float dpart[PPB * 65];   // padded stride 65
    __shared__ float dqr[PPB * 9];      // padded stride 9
    __shared__ float y2_s[PPB], e_s[PPB], d_s[PPB], w_s[PPB], sA_s[PPB], fx_s[PPB];
    __shared__ float pseg[NWAVE * DDIM];

    unsigned barno = 0;

    // ---- register-resident x chunk (loaded once) ----
    float4 xreg[PPW];
    #pragma unroll
    for (int i = 0; i < PPW; ++i)
        xreg[i] = xr[(wv * PPW + i) * 64 + lane];

    // batched per-point dot vs broadcast vector
    auto dot_rows = [&](float4 v4, float* dst, bool self) {
        #pragma unroll
        for (int i = 0; i < PPW; ++i) {
            float4 xv = xreg[i];
            float4 u4 = self ? xv : v4;
            dpart[(wv * PPW + i) * 65 + lane] =
                xv.x * u4.x + xv.y * u4.y + xv.z * u4.z + xv.w * u4.w;
        }
        __syncthreads();
        {
            int pl = t & 127, q = t >> 7;
            float s = 0.f;
            #pragma unroll
            for (int j = 0; j < 8; ++j) s += dpart[pl * 65 + q * 8 + j];
            dqr[pl * 9 + q] = s;
        }
        __syncthreads();
        if (t < PPB) {
            float s = 0.f;
            #pragma unroll
            for (int j = 0; j < 8; ++j) s += dqr[t * 9 + j];
            dst[t] = s;
        }
        __syncthreads();
    };

    // weighted column sum over register x -> sc1 store of row vector part
    auto wsum_rows = [&](const float* wgt, float* dstv) {
        float4 a = make_float4(0.f, 0.f, 0.f, 0.f);
        #pragma unroll
        for (int i = 0; i < PPW; ++i) {
            float w = wgt ? wgt[wv * PPW + i] : 1.f;
            a.x += w * xreg[i].x; a.y += w * xreg[i].y;
            a.z += w * xreg[i].z; a.w += w * xreg[i].w;
        }
        __syncthreads();
        ((float4*)(pseg + wv * DDIM))[lane] = a;
        __syncthreads();
        float s = 0.f;
        if (t < DDIM) {
            #pragma unroll
            for (int w = 0; w < NWAVE; ++w) s += pseg[w * DDIM + t];
        }
        float partner = __shfl_xor(s, 1);      // wave-uniform exec
        if (t < DDIM && !(t & 1))
            st_pair_sc1(dstv + t, s, partner);
    };

    // publish: drain all row stores, then tag this block's row
    auto publish = [&](float* buf) {
        __syncthreads();
        if (t == 0) st_u_sc1((unsigned*)(buf + b * PSTR + 258), barno);
    };
    // wait: 128 threads spin on 128 distinct tag lines (monotonic, >=)
    auto wait_tags = [&](const float* buf) {
        if (t < NBLK) {
            const unsigned* tg = (const unsigned*)(buf + t * PSTR + 258);
            while (ld_u_sc1(tg) < barno) {}
        }
        __syncthreads();
    };

    // cross-block vector reduce over 128 rows
    auto reduce128 = [&](const float* buf, float* dstv) {
        const int dg = t & 127, sg = t >> 7;
        float ax = 0.f, ay = 0.f;
        #pragma unroll
        for (int j = 0; j < 16; ++j) {
            float2 v = ld_pair_sc1(buf + (sg * 16 + j) * PSTR + 2 * dg);
            ax += v.x; ay += v.y;
        }
        __syncthreads();
        ((float2*)(pseg + sg * DDIM))[dg] = make_float2(ax, ay);
        __syncthreads();
        if (t < DDIM) {
            float s = 0.f;
            #pragma unroll
            for (int w = 0; w < 8; ++w) s += pseg[w * DDIM + t];
            dstv[t] = s;
        }
        __syncthreads();
    };

    // ---- om = exp0(mean_param) ----
    {
        float u = (t < DDIM) ? mean_param[t] : 0.f;
        float un2 = block_sum(u * u);
        float un = sqrtf(fmaxf(un2, EPSF));
        if (t < DDIM) om_s[t] = tanhf(sc * un) * u / (sc * un);
    }
    float om2;
    { float v = (t < DDIM) ? om_s[t] * om_s[t] : 0.f; om2 = block_sum(v); }

    // ---- y2, e = <om,x> ----
    dot_rows(make_float4(0.f, 0.f, 0.f, 0.f), y2_s, true);
    {
        float4 om4 = ((const float4*)om_s)[lane];
        dot_rows(om4, e_s, false);
    }

    // ---- mean partial ----
    ++barno;
    wsum_rows(nullptr, PA + b * PSTR);
    publish(PA);
    wait_tags(PA);

    // ---- init mu ----
    float mu2;
    {
        reduce128(PA, g_s);
        float m = (t < DDIM) ? g_s[t] * N1 : 0.f;
        float mn2 = block_sum(m * m);
        float mn = sqrtf(fmaxf(mn2, EPSF));
        float maxn = (1.f - 1e-3f) / sc;
        float f = fminf(1.f, maxn / mn);
        if (t < DDIM) mu_s[t] = m * f;
        mu2 = f * f * mn2;                  // analytic ||mu||^2
        __syncthreads();                    // mu_s visible before dot_rows
    }

    // ---- Karcher iterations ----
    for (int it = 0; it < FRECHET_ITERS_N; ++it) {
        float* buf = (it & 1) ? PA : PB;
        ++barno;
        {
            float4 mu4 = ((const float4*)mu_s)[lane];
            dot_rows(mu4, d_s, false);
        }
        if (t < PPB) {
            float y2 = y2_s[t], d = d_s[t];
            float P = 1.f - 2.f * c * d;
            float den = fmaxf(P + c * c * mu2 * y2, EPSF);
            float A = -(P + c * y2) / den;
            float B = (1.f - c * mu2) / den;
            float mn2 = fmaxf(A * A * mu2 + 2.f * A * B * d + B * B * y2, EPSF);
            float mn = sqrtf(mn2);
            float tt = atanhf(fminf(sc * mn, TCLIP));
            float s = (fmaxf(1.f - c * mu2, EPSF) / sc) * tt / mn;
            w_s[t] = s * B;
            sA_s[t] = s * A;
        }
        __syncthreads();
        wsum_rows(w_s, buf + b * PSTR);
        float sAl = (t < PPB) ? sA_s[t] : 0.f;
        float wdl = (t < PPB) ? w_s[t] * d_s[t] : 0.f;   // <mu,V> local part
        block_sum2(sAl, wdl);
        if (t == 0) st_pair_sc1(buf + b * PSTR + 256, sAl, wdl);
        publish(buf);
        wait_tags(buf);

        // finalize: mu <- expmap(mu, g) with scalarized norms
        reduce128(buf, g_s);                 // V
        float vv  = (t < DDIM) ? g_s[t] * g_s[t] : 0.f;
        float2 sp = make_float2(0.f, 0.f);
        if (t < NBLK) sp = ld_pair_sc1(buf + t * PSTR + 256);
        float sAt = sp.x, wdt = sp.y;
        block_sum3(vv, sAt, wdt);            // VV, sum sA, <mu,V>
        float gn2 = N1 * N1 * (vv + 2.f * sAt * wdt + sAt * sAt * mu2);
        float mg  = N1 * (wdt + sAt * mu2);
        float un = sqrtf(fmaxf(gn2, EPSF));
        float lam = 2.f / fmaxf(1.f - c * mu2, EPSF);
        float k = tanhf(sc * lam * un * 0.5f) / (sc * un);
        float ms = k * mg;
        float s2 = k * k * gn2;
        float aa = 1.f + 2.f * c * ms + c * s2;
        float bb2 = 1.f - c * mu2;
        float den = fmaxf(1.f + 2.f * c * ms + c * c * mu2 * s2, EPSF);
        float cm = (aa + bb2 * k * N1 * sAt) / den;
        float cv = (bb2 * k * N1) / den;
        if (t < DDIM) mu_s[t] = cm * mu_s[t] + cv * g_s[t];
        mu2 = cm * cm * mu2 + 2.f * cm * cv * wdt + cv * cv * vv;   // analytic
        __syncthreads();                    // mu_s visible before next dot_rows
    }

    // ---- variance pass ----
    float* vbuf = ((FRECHET_ITERS_N - 1) & 1) ? PB : PA;
    ++barno;
    {
        float4 mu4 = ((const float4*)mu_s)[lane];
        dot_rows(mu4, d_s, false);   // d_s kept for output chain
    }
    if (t < PPB) {
        float y2 = y2_s[t], d = d_s[t];
        float P = 1.f - 2.f * c * d;
        float den = fmaxf(P + c * c * mu2 * y2, EPSF);
        float A = -(P + c * y2) / den;
        float B = (1.f - c * mu2) / den;
        float mn2 = fmaxf(A * A * mu2 + 2.f * A * B * d + B * B * y2, EPSF);
        float mn = sqrtf(mn2);
        float tt = atanhf(fminf(sc * mn, TCLIP));
        float dd = (2.f / sc) * tt;
        sA_s[t] = dd * dd;
    }
    __syncthreads();
    {
        float v = (t < PPB) ? sA_s[t] : 0.f;
        float tot = block_sum(v);
        if (t == 0) st_f_sc1(vbuf + b * PSTR + 256, tot);
    }
    publish(vbuf);
    wait_tags(vbuf);

    float va = (t < NBLK) ? __hip_atomic_load(vbuf + t * PSTR + 256,
                 __ATOMIC_RELAXED, __HIP_MEMORY_SCOPE_AGENT) : 0.f;
    float ob = (t < DDIM) ? om_s[t] * mu_s[t] : 0.f;
    block_sum2(va, ob);                      // var sum, omu
    float var = va * N1;
    float gamma = sqrtf(var_param[0] / (var + 1e-6f));
    float omu = ob;

    const float Amu = fmaxf(1.f - c * mu2, EPSF);
    const float Aom = fmaxf(1.f - c * om2, EPSF);
    const float ratio = Aom / Amu;           // lam_mu / lam_om
    const float aq = 1.f - 2.f * c * omu + c * mu2;
    const float bq = 1.f - c * om2;
    const float dqv = fmaxf(1.f - 2.f * c * omu + c * c * om2 * mu2, EPSF);
    const float qo = aq / dqv, qm = -bq / dqv;
    const float q2 = qo * qo * om2 + 2.f * qo * qm * omu + qm * qm * mu2;
    const float lam_om = 2.f / Aom;

    // ---- output chain: one thread per point ----
    if (t < PPB) {
        float y2 = y2_s[t], d = d_s[t], e = e_s[t];
        auto dotOm3 = [&](float po, float pm, float px) { return po * om2 + pm * omu + px * e; };
        auto dotMu3 = [&](float po, float pm, float px) { return po * omu + pm * mu2 + px * d; };
        auto sqn3 = [&](float po, float pm, float px) {
            return po * po * om2 + pm * pm * mu2 + px * px * y2
                 + 2.f * (po * pm * omu + po * px * e + pm * px * d);
        };

        float P = 1.f - 2.f * c * d;
        float den0 = fmaxf(P + c * c * mu2 * y2, EPSF);
        float A = -(P + c * y2) / den0;
        float B = (1.f - c * mu2) / den0;
        float mn2 = fmaxf(A * A * mu2 + 2.f * A * B * d + B * B * y2, EPSF);
        float mn = sqrtf(mn2);
        float tt = atanhf(fminf(sc * mn, TCLIP));
        float s = (fmaxf(1.f - c * mu2, EPSF) / sc) * tt / mn;
        float Um = s * A, Ux = s * B;

        float xy1 = -dotMu3(0.f, Um, Ux);
        float Y21 = sqn3(0.f, Um, Ux);
        float a1 = 1.f + 2.f * c * xy1 + c * Y21;
        float b1 = 1.f - c * mu2;
        float dn1 = fmaxf(1.f + 2.f * c * xy1 + c * c * mu2 * Y21, EPSF);
        float h1m = (-a1 + b1 * Um) / dn1;
        float h1x = (b1 * Ux) / dn1;

        float xy2 = dotOm3(0.f, h1m, h1x);
        float Y22 = sqn3(0.f, h1m, h1x);
        float a2 = 1.f + 2.f * c * xy2 + c * Y22;
        float b2 = 1.f - c * om2;
        float dn2 = fmaxf(1.f + 2.f * c * xy2 + c * c * om2 * Y22, EPSF);
        float h2o = a2 / dn2;
        float h2m = (b2 * h1m) / dn2;
        float h2x = (b2 * h1x) / dn2;

        float xy3 = -(qo * dotOm3(h2o, h2m, h2x) + qm * dotMu3(h2o, h2m, h2x));
        float Y23 = sqn3(h2o, h2m, h2x);
        float a3 = 1.f + 2.f * c * xy3 + c * Y23;
        float b3 = 1.f - c * q2;
        float dn3 = fmaxf(1.f + 2.f * c * xy3 + c * c * q2 * Y23, EPSF);
        float g2o = (-a3 * qo + b3 * h2o) / dn3;
        float g2m = (-a3 * qm + b3 * h2m) / dn3;
        float g2x = (b3 * h2x) / dn3;

        float k1 = ratio * gamma;
        float Lo = k1 * g2o, Lm = k1 * g2m, Lx = k1 * g2x;
        float un2 = sqn3(Lo, Lm, Lx);
        float un = sqrtf(fmaxf(un2, EPSF));
        float coef = tanhf(sc * lam_om * un * 0.5f) / (sc * un);
        float So = coef * Lo, Sm = coef * Lm, Sx = coef * Lx;
        float xy4 = dotOm3(So, Sm, Sx);
        float Y24 = coef * coef * un2;
        float a4 = 1.f + 2.f * c * xy4 + c * Y24;
        float b4 = 1.f - c * om2;
        float dn4 = fmaxf(1.f + 2.f * c * xy4 + c * c * om2 * Y24, EPSF);
        w_s[t]  = (a4 + b4 * So) / dn4;   // fo
        sA_s[t] = (b4 * Sm) / dn4;        // fm
        fx_s[t] = (b4 * Sx) / dn4;        // fx
    }
    __syncthreads();

    // ---- output store from registers ----
    {
        float4 mu4f = ((const float4*)mu_s)[lane];
        float4 om4f = ((const float4*)om_s)[lane];
        #pragma unroll
        for (int i = 0; i < PPW; ++i) {
            int pl = wv * PPW + i;
            float fo = w_s[pl], fm = sA_s[pl], fx = fx_s[pl];
            float4 x4 = xreg[i];
            float4 o4;
            o4.x = fo * om4f.x + fm * mu4f.x + fx * x4.x;
            o4.y = fo * om4f.y + fm * mu4f.y + fx * x4.y;
            o4.z = fo * om4f.z + fm * mu4f.z + fx * x4.z;
            o4.w = fo * om4f.w + fm * mu4f.w + fx * x4.w;
            ((float4*)out)[(p0 + pl) * 64 + lane] = o4;
        }
    }
}

extern "C" void kernel_launch(void* const* d_in, const int* in_sizes, int n_in,
                              void* d_out, int out_size, void* d_ws, size_t ws_size,
                              hipStream_t stream) {
    const float* x = (const float*)d_in[0];
    const float* K = (const float*)d_in[1];
    const float* mean_param = (const float*)d_in[2];
    const float* var_param = (const float*)d_in[3];
    float* out = (float*)d_out;
    float* ws = (float*)d_ws;

    init_tags<<<1, 256, 0, stream>>>(ws);
    void* args[] = {(void*)&x, (void*)&K, (void*)&mean_param, (void*)&var_param,
                    (void*)&out, (void*)&ws};
    hipLaunchCooperativeKernel((const void*)rbn_fused, dim3(NBLK), dim3(NTHR),
                               args, 0, stream);
}

// Round 8
// 205.756 us; speedup vs baseline: 1.0065x; 1.0065x over previous
//
#include <hip/hip_runtime.h>
#include <math.h>
#include <string.h>

#define EPSF 1e-6f
#define TCLIP (1.0f - 1e-5f)
#define NPTS 16384
#define DDIM 256
#define NBLK 128
#define NTHR 1024
#define PPB 128   // points per block
#define NWAVE 16
#define PPW 8     // points per wave (registers: 8 x float4 = 32 VGPRs)
#define PSTR 260  // row: 256 vec + sA@256 + wd@257 + tag@258 + pad
#define FRECHET_ITERS_N 10

// ws float layout: two partial buffers, all accesses via sc1 (coherent path)
#define WS_PA 64
#define WS_PB (WS_PA + NBLK * PSTR)

// --- coherent-path (sc1) accessors: bypass L2 both ways, no fences needed ---
__device__ __forceinline__ void st_pair_sc1(float* addr, float a, float b) {
    float2 f2 = make_float2(a, b);
    double dv; memcpy(&dv, &f2, 8);
    __hip_atomic_store((double*)addr, dv, __ATOMIC_RELAXED, __HIP_MEMORY_SCOPE_AGENT);
}
__device__ __forceinline__ float2 ld_pair_sc1(const float* addr) {
    double dv = __hip_atomic_load((const double*)addr, __ATOMIC_RELAXED, __HIP_MEMORY_SCOPE_AGENT);
    float2 f2; memcpy(&f2, &dv, 8);
    return f2;
}
__device__ __forceinline__ void st_f_sc1(float* addr, float v) {
    __hip_atomic_store(addr, v, __ATOMIC_RELAXED, __HIP_MEMORY_SCOPE_AGENT);
}
__device__ __forceinline__ void st_u_sc1(unsigned* addr, unsigned v) {
    __hip_atomic_store(addr, v, __ATOMIC_RELAXED, __HIP_MEMORY_SCOPE_AGENT);
}
__device__ __forceinline__ unsigned ld_u_sc1(const unsigned* addr) {
    return __hip_atomic_load(addr, __ATOMIC_RELAXED, __HIP_MEMORY_SCOPE_AGENT);
}

__device__ __forceinline__ float block_sum(float v) {
    __shared__ float s_bs[NWAVE];
    #pragma unroll
    for (int off = 32; off; off >>= 1) v += __shfl_xor(v, off);
    const int w = threadIdx.x >> 6, l = threadIdx.x & 63;
    __syncthreads();
    if (l == 0) s_bs[w] = v;
    __syncthreads();
    float s = 0.f;
    #pragma unroll
    for (int i = 0; i < NWAVE; ++i) s += s_bs[i];
    return s;
}

__device__ __forceinline__ void block_sum2(float& a, float& b) {
    __shared__ float sa2[NWAVE], sb2[NWAVE];
    #pragma unroll
    for (int off = 32; off; off >>= 1) { a += __shfl_xor(a, off); b += __shfl_xor(b, off); }
    const int w = threadIdx.x >> 6, l = threadIdx.x & 63;
    __syncthreads();
    if (l == 0) { sa2[w] = a; sb2[w] = b; }
    __syncthreads();
    a = 0.f; b = 0.f;
    #pragma unroll
    for (int i = 0; i < NWAVE; ++i) { a += sa2[i]; b += sb2[i]; }
}

__device__ __forceinline__ void block_sum3(float& a, float& b, float& cc) {
    __shared__ float sa3[NWAVE], sb3[NWAVE], sc3[NWAVE];
    #pragma unroll
    for (int off = 32; off; off >>= 1) {
        a += __shfl_xor(a, off); b += __shfl_xor(b, off); cc += __shfl_xor(cc, off);
    }
    const int w = threadIdx.x >> 6, l = threadIdx.x & 63;
    __syncthreads();
    if (l == 0) { sa3[w] = a; sb3[w] = b; sc3[w] = cc; }
    __syncthreads();
    a = 0.f; b = 0.f; cc = 0.f;
    #pragma unroll
    for (int i = 0; i < NWAVE; ++i) { a += sa3[i]; b += sb3[i]; cc += sc3[i]; }
}

// zero all tag slots via sc1 (ws is poisoned to 0xAA -> would read as "arrived")
__global__ void init_tags(float* ws) {
    int t = threadIdx.x;
    if (t < NBLK) {
        st_u_sc1((unsigned*)(ws + WS_PA + t * PSTR + 258), 0u);
        st_u_sc1((unsigned*)(ws + WS_PB + t * PSTR + 258), 0u);
    }
}

__global__ __launch_bounds__(NTHR, 1) void rbn_fused(
    const float* __restrict__ x, const float* __restrict__ Kp,
    const float* __restrict__ mean_param, const float* __restrict__ var_param,
    float* __restrict__ out, float* __restrict__ ws)
{
    const float c = -Kp[0];
    const float sc = sqrtf(c);
    const float N1 = 1.f / NPTS;
    const int t = threadIdx.x, lane = t & 63, wv = t >> 6;
    const int b = blockIdx.x;
    const int p0 = b * PPB;
    const float4* xr = ((const float4*)x) + p0 * 64;

    float* PA = ws + WS_PA;
    float* PB = ws + WS_PB;

    __shared__ float mu_s[DDIM], om_s[DDIM], g_s[DDIM];
    __shared__ float dpart[PPB * 65];   // padded stride 65
    __shared__ float dqr[PPB * 9];      // padded stride 9
    __shared__ float y2_s[PPB], e_s[PPB], d_s[PPB], w_s[PPB], sA_s[PPB], fx_s[PPB];
    __shared__ float pseg[NWAVE * DDIM];

    unsigned barno = 0;

    // ---- register-resident x chunk (loaded once) ----
    float4 xreg[PPW];
    #pragma unroll
    for (int i = 0; i < PPW; ++i)
        xreg[i] = xr[(wv * PPW + i) * 64 + lane];

    // batched per-point dot vs broadcast vector
    auto dot_rows = [&](float4 v4, float* dst, bool self) {
        #pragma unroll
        for (int i = 0; i < PPW; ++i) {
            float4 xv = xreg[i];
            float4 u4 = self ? xv : v4;
            dpart[(wv * PPW + i) * 65 + lane] =
                xv.x * u4.x + xv.y * u4.y + xv.z * u4.z + xv.w * u4.w;
        }
        __syncthreads();
        {
            int pl = t & 127, q = t >> 7;
            float s = 0.f;
            #pragma unroll
            for (int j = 0; j < 8; ++j) s += dpart[pl * 65 + q * 8 + j];
            dqr[pl * 9 + q] = s;
        }
        __syncthreads();
        if (t < PPB) {
            float s = 0.f;
            #pragma unroll
            for (int j = 0; j < 8; ++j) s += dqr[t * 9 + j];
            dst[t] = s;
        }
        __syncthreads();
    };

    // weighted column sum over register x -> sc1 store of row vector part
    auto wsum_rows = [&](const float* wgt, float* dstv) {
        float4 a = make_float4(0.f, 0.f, 0.f, 0.f);
        #pragma unroll
        for (int i = 0; i < PPW; ++i) {
            float w = wgt ? wgt[wv * PPW + i] : 1.f;
            a.x += w * xreg[i].x; a.y += w * xreg[i].y;
            a.z += w * xreg[i].z; a.w += w * xreg[i].w;
        }
        __syncthreads();
        ((float4*)(pseg + wv * DDIM))[lane] = a;
        __syncthreads();
        float s = 0.f;
        if (t < DDIM) {
            #pragma unroll
            for (int w = 0; w < NWAVE; ++w) s += pseg[w * DDIM + t];
        }
        float partner = __shfl_xor(s, 1);      // wave-uniform exec
        if (t < DDIM && !(t & 1))
            st_pair_sc1(dstv + t, s, partner);
    };

    // publish: drain all row stores (syncthreads drains vmcnt), then tag row
    auto publish = [&](float* buf) {
        __syncthreads();
        if (t == 0) st_u_sc1((unsigned*)(buf + b * PSTR + 258), barno);
    };
    // wait: 128 threads spin on 128 distinct tag lines WITH sleep backoff
    auto wait_tags = [&](const float* buf) {
        if (t < NBLK) {
            const unsigned* tg = (const unsigned*)(buf + t * PSTR + 258);
            while (ld_u_sc1(tg) < barno)
                __builtin_amdgcn_s_sleep(1);
        }
        __syncthreads();
    };

    // cross-block vector reduce over 128 rows; g-outputs consumed only by the
    // writing thread, so no trailing sync needed
    auto reduce128 = [&](const float* buf, float* dstv) {
        const int dg = t & 127, sg = t >> 7;
        float ax = 0.f, ay = 0.f;
        #pragma unroll
        for (int j = 0; j < 16; ++j) {
            float2 v = ld_pair_sc1(buf + (sg * 16 + j) * PSTR + 2 * dg);
            ax += v.x; ay += v.y;
        }
        __syncthreads();                 // pseg reuse guard
        ((float2*)(pseg + sg * DDIM))[dg] = make_float2(ax, ay);
        __syncthreads();
        if (t < DDIM) {
            float s = 0.f;
            #pragma unroll
            for (int w = 0; w < 8; ++w) s += pseg[w * DDIM + t];
            dstv[t] = s;
        }
    };

    // ---- om = exp0(mean_param) ----
    {
        float u = (t < DDIM) ? mean_param[t] : 0.f;
        float un2 = block_sum(u * u);
        float un = sqrtf(fmaxf(un2, EPSF));
        if (t < DDIM) om_s[t] = tanhf(sc * un) * u / (sc * un);
    }
    float om2;
    { float v = (t < DDIM) ? om_s[t] * om_s[t] : 0.f; om2 = block_sum(v); }

    // ---- y2, e = <om,x> ----
    dot_rows(make_float4(0.f, 0.f, 0.f, 0.f), y2_s, true);
    {
        float4 om4 = ((const float4*)om_s)[lane];
        dot_rows(om4, e_s, false);
    }

    // ---- mean partial ----
    ++barno;
    wsum_rows(nullptr, PA + b * PSTR);
    publish(PA);
    wait_tags(PA);

    // ---- init mu ----
    float mu2;
    {
        reduce128(PA, g_s);
        float m = (t < DDIM) ? g_s[t] * N1 : 0.f;
        float mn2 = block_sum(m * m);
        float mn = sqrtf(fmaxf(mn2, EPSF));
        float maxn = (1.f - 1e-3f) / sc;
        float f = fminf(1.f, maxn / mn);
        if (t < DDIM) mu_s[t] = m * f;
        mu2 = f * f * mn2;                  // analytic ||mu||^2
        __syncthreads();                    // mu_s visible before dot_rows
    }

    // ---- Karcher iterations ----
    for (int it = 0; it < FRECHET_ITERS_N; ++it) {
        float* buf = (it & 1) ? PA : PB;
        ++barno;
        {
            float4 mu4 = ((const float4*)mu_s)[lane];
            dot_rows(mu4, d_s, false);
        }
        if (t < PPB) {
            float y2 = y2_s[t], d = d_s[t];
            float P = 1.f - 2.f * c * d;
            float den = fmaxf(P + c * c * mu2 * y2, EPSF);
            float A = -(P + c * y2) / den;
            float B = (1.f - c * mu2) / den;
            float mn2 = fmaxf(A * A * mu2 + 2.f * A * B * d + B * B * y2, EPSF);
            float mn = sqrtf(mn2);
            float tt = atanhf(fminf(sc * mn, TCLIP));
            float s = (fmaxf(1.f - c * mu2, EPSF) / sc) * tt / mn;
            w_s[t] = s * B;
            sA_s[t] = s * A;
        }
        __syncthreads();
        wsum_rows(w_s, buf + b * PSTR);
        float sAl = (t < PPB) ? sA_s[t] : 0.f;
        float wdl = (t < PPB) ? w_s[t] * d_s[t] : 0.f;   // <mu,V> local part
        block_sum2(sAl, wdl);
        if (t == 0) st_pair_sc1(buf + b * PSTR + 256, sAl, wdl);
        publish(buf);
        wait_tags(buf);

        // finalize: mu <- expmap(mu, g) with scalarized norms
        reduce128(buf, g_s);                 // V (per-thread t<DDIM)
        float vv  = (t < DDIM) ? g_s[t] * g_s[t] : 0.f;
        float2 sp = make_float2(0.f, 0.f);
        if (t < NBLK) sp = ld_pair_sc1(buf + t * PSTR + 256);
        float sAt = sp.x, wdt = sp.y;
        block_sum3(vv, sAt, wdt);            // VV, sum sA, <mu,V>
        float gn2 = N1 * N1 * (vv + 2.f * sAt * wdt + sAt * sAt * mu2);
        float mg  = N1 * (wdt + sAt * mu2);
        float un = sqrtf(fmaxf(gn2, EPSF));
        float lam = 2.f / fmaxf(1.f - c * mu2, EPSF);
        float k = tanhf(sc * lam * un * 0.5f) / (sc * un);
        float ms = k * mg;
        float s2 = k * k * gn2;
        float aa = 1.f + 2.f * c * ms + c * s2;
        float bb2 = 1.f - c * mu2;
        float den = fmaxf(1.f + 2.f * c * ms + c * c * mu2 * s2, EPSF);
        float cm = (aa + bb2 * k * N1 * sAt) / den;
        float cv = (bb2 * k * N1) / den;
        if (t < DDIM) mu_s[t] = cm * mu_s[t] + cv * g_s[t];
        mu2 = cm * cm * mu2 + 2.f * cm * cv * wdt + cv * cv * vv;   // analytic
        __syncthreads();                    // mu_s visible before next dot_rows
    }

    // ---- variance pass ----
    float* vbuf = ((FRECHET_ITERS_N - 1) & 1) ? PB : PA;
    ++barno;
    {
        float4 mu4 = ((const float4*)mu_s)[lane];
        dot_rows(mu4, d_s, false);   // d_s kept for output chain
    }
    if (t < PPB) {
        float y2 = y2_s[t], d = d_s[t];
        float P = 1.f - 2.f * c * d;
        float den = fmaxf(P + c * c * mu2 * y2, EPSF);
        float A = -(P + c * y2) / den;
        float B = (1.f - c * mu2) / den;
        float mn2 = fmaxf(A * A * mu2 + 2.f * A * B * d + B * B * y2, EPSF);
        float mn = sqrtf(mn2);
        float tt = atanhf(fminf(sc * mn, TCLIP));
        float dd = (2.f / sc) * tt;
        sA_s[t] = dd * dd;
    }
    __syncthreads();
    {
        float v = (t < PPB) ? sA_s[t] : 0.f;
        float tot = block_sum(v);
        if (t == 0) st_f_sc1(vbuf + b * PSTR + 256, tot);
    }
    publish(vbuf);
    wait_tags(vbuf);

    float va = (t < NBLK) ? __hip_atomic_load(vbuf + t * PSTR + 256,
                 __ATOMIC_RELAXED, __HIP_MEMORY_SCOPE_AGENT) : 0.f;
    float ob = (t < DDIM) ? om_s[t] * mu_s[t] : 0.f;
    block_sum2(va, ob);                      // var sum, omu
    float var = va * N1;
    float gamma = sqrtf(var_param[0] / (var + 1e-6f));
    float omu = ob;

    const float Amu = fmaxf(1.f - c * mu2, EPSF);
    const float Aom = fmaxf(1.f - c * om2, EPSF);
    const float ratio = Aom / Amu;           // lam_mu / lam_om
    const float aq = 1.f - 2.f * c * omu + c * mu2;
    const float bq = 1.f - c * om2;
    const float dqv = fmaxf(1.f - 2.f * c * omu + c * c * om2 * mu2, EPSF);
    const float qo = aq / dqv, qm = -bq / dqv;
    const float q2 = qo * qo * om2 + 2.f * qo * qm * omu + qm * qm * mu2;
    const float lam_om = 2.f / Aom;

    // ---- output chain: one thread per point ----
    if (t < PPB) {
        float y2 = y2_s[t], d = d_s[t], e = e_s[t];
        auto dotOm3 = [&](float po, float pm, float px) { return po * om2 + pm * omu + px * e; };
        auto dotMu3 = [&](float po, float pm, float px) { return po * omu + pm * mu2 + px * d; };
        auto sqn3 = [&](float po, float pm, float px) {
            return po * po * om2 + pm * pm * mu2 + px * px * y2
                 + 2.f * (po * pm * omu + po * px * e + pm * px * d);
        };

        float P = 1.f - 2.f * c * d;
        float den0 = fmaxf(P + c * c * mu2 * y2, EPSF);
        float A = -(P + c * y2) / den0;
        float B = (1.f - c * mu2) / den0;
        float mn2 = fmaxf(A * A * mu2 + 2.f * A * B * d + B * B * y2, EPSF);
        float mn = sqrtf(mn2);
        float tt = atanhf(fminf(sc * mn, TCLIP));
        float s = (fmaxf(1.f - c * mu2, EPSF) / sc) * tt / mn;
        float Um = s * A, Ux = s * B;

        float xy1 = -dotMu3(0.f, Um, Ux);
        float Y21 = sqn3(0.f, Um, Ux);
        float a1 = 1.f + 2.f * c * xy1 + c * Y21;
        float b1 = 1.f - c * mu2;
        float dn1 = fmaxf(1.f + 2.f * c * xy1 + c * c * mu2 * Y21, EPSF);
        float h1m = (-a1 + b1 * Um) / dn1;
        float h1x = (b1 * Ux) / dn1;

        float xy2 = dotOm3(0.f, h1m, h1x);
        float Y22 = sqn3(0.f, h1m, h1x);
        float a2 = 1.f + 2.f * c * xy2 + c * Y22;
        float b2 = 1.f - c * om2;
        float dn2 = fmaxf(1.f + 2.f * c * xy2 + c * c * om2 * Y22, EPSF);
        float h2o = a2 / dn2;
        float h2m = (b2 * h1m) / dn2;
        float h2x = (b2 * h1x) / dn2;

        float xy3 = -(qo * dotOm3(h2o, h2m, h2x) + qm * dotMu3(h2o, h2m, h2x));
        float Y23 = sqn3(h2o, h2m, h2x);
        float a3 = 1.f + 2.f * c * xy3 + c * Y23;
        float b3 = 1.f - c * q2;
        float dn3 = fmaxf(1.f + 2.f * c * xy3 + c * c * q2 * Y23, EPSF);
        float g2o = (-a3 * qo + b3 * h2o) / dn3;
        float g2m = (-a3 * qm + b3 * h2m) / dn3;
        float g2x = (b3 * h2x) / dn3;

        float k1 = ratio * gamma;
        float Lo = k1 * g2o, Lm = k1 * g2m, Lx = k1 * g2x;
        float un2 = sqn3(Lo, Lm, Lx);
        float un = sqrtf(fmaxf(un2, EPSF));
        float coef = tanhf(sc * lam_om * un * 0.5f) / (sc * un);
        float So = coef * Lo, Sm = coef * Lm, Sx = coef * Lx;
        float xy4 = dotOm3(So, Sm, Sx);
        float Y24 = coef * coef * un2;
        float a4 = 1.f + 2.f * c * xy4 + c * Y24;
        float b4 = 1.f - c * om2;
        float dn4 = fmaxf(1.f + 2.f * c * xy4 + c * c * om2 * Y24, EPSF);
        w_s[t]  = (a4 + b4 * So) / dn4;   // fo
        sA_s[t] = (b4 * Sm) / dn4;        // fm
        fx_s[t] = (b4 * Sx) / dn4;        // fx
    }
    __syncthreads();

    // ---- output store from registers ----
    {
        float4 mu4f = ((const float4*)mu_s)[lane];
        float4 om4f = ((const float4*)om_s)[lane];
        #pragma unroll
        for (int i = 0; i < PPW; ++i) {
            int pl = wv * PPW + i;
            float fo = w_s[pl], fm = sA_s[pl], fx = fx_s[pl];
            float4 x4 = xreg[i];
            float4 o4;
            o4.x = fo * om4f.x + fm * mu4f.x + fx * x4.x;
            o4.y = fo * om4f.y + fm * mu4f.y + fx * x4.y;
            o4.z = fo * om4f.z + fm * mu4f.z + fx * x4.z;
            o4.w = fo * om4f.w + fm * mu4f.w + fx * x4.w;
            ((float4*)out)[(p0 + pl) * 64 + lane] = o4;
        }
    }
}

extern "C" void kernel_launch(void* const* d_in, const int* in_sizes, int n_in,
                              void* d_out, int out_size, void* d_ws, size_t ws_size,
                              hipStream_t stream) {
    const float* x = (const float*)d_in[0];
    const float* K = (const float*)d_in[1];
    const float* mean_param = (const float*)d_in[2];
    const float* var_param = (const float*)d_in[3];
    float* out = (float*)d_out;
    float* ws = (float*)d_ws;

    init_tags<<<1, 256, 0, stream>>>(ws);
    void* args[] = {(void*)&x, (void*)&K, (void*)&mean_param, (void*)&var_param,
                    (void*)&out, (void*)&ws};
    hipLaunchCooperativeKernel((const void*)rbn_fused, dim3(NBLK), dim3(NTHR),
                               args, 0, stream);
}

// Round 9
// 188.119 us; speedup vs baseline: 1.1009x; 1.0938x over previous
//
#include <hip/hip_runtime.h>
#include <math.h>
#include <string.h>

#define EPSF 1e-6f
#define TCLIP (1.0f - 1e-5f)
#define NPTS 16384
#define DDIM 256
#define NBLK 128
#define NTHR 1024
#define PPB 128   // points per block
#define NWAVE 16
#define PPW 8     // points per wave (registers: 8 x float4 = 32 VGPRs)
#define PSTR 260  // row: 256 vec + sA@256 + wd@257 + tag@258 + pad
#define FRECHET_ITERS_N 10

#define WS_PA 64
#define WS_PB (WS_PA + NBLK * PSTR)

// --- coherent-path (sc1) accessors ---
__device__ __forceinline__ void st_pair_sc1(float* addr, float a, float b) {
    float2 f2 = make_float2(a, b);
    double dv; memcpy(&dv, &f2, 8);
    __hip_atomic_store((double*)addr, dv, __ATOMIC_RELAXED, __HIP_MEMORY_SCOPE_AGENT);
}
__device__ __forceinline__ float2 ld_pair_sc1(const float* addr) {
    double dv = __hip_atomic_load((const double*)addr, __ATOMIC_RELAXED, __HIP_MEMORY_SCOPE_AGENT);
    float2 f2; memcpy(&f2, &dv, 8);
    return f2;
}
__device__ __forceinline__ void st_f_sc1(float* addr, float v) {
    __hip_atomic_store(addr, v, __ATOMIC_RELAXED, __HIP_MEMORY_SCOPE_AGENT);
}
__device__ __forceinline__ float ld_f_sc1(const float* addr) {
    return __hip_atomic_load(addr, __ATOMIC_RELAXED, __HIP_MEMORY_SCOPE_AGENT);
}
__device__ __forceinline__ void st_u_sc1(unsigned* addr, unsigned v) {
    __hip_atomic_store(addr, v, __ATOMIC_RELAXED, __HIP_MEMORY_SCOPE_AGENT);
}
__device__ __forceinline__ unsigned ld_u_sc1(const unsigned* addr) {
    return __hip_atomic_load(addr, __ATOMIC_RELAXED, __HIP_MEMORY_SCOPE_AGENT);
}

__device__ __forceinline__ float block_sum(float v) {
    __shared__ float s_bs[NWAVE];
    #pragma unroll
    for (int off = 32; off; off >>= 1) v += __shfl_xor(v, off);
    const int w = threadIdx.x >> 6, l = threadIdx.x & 63;
    __syncthreads();
    if (l == 0) s_bs[w] = v;
    __syncthreads();
    float s = 0.f;
    #pragma unroll
    for (int i = 0; i < NWAVE; ++i) s += s_bs[i];
    return s;
}

__global__ void init_tags(float* ws) {
    int t = threadIdx.x;
    if (t < NBLK) {
        st_u_sc1((unsigned*)(ws + WS_PA + t * PSTR + 258), 0u);
        st_u_sc1((unsigned*)(ws + WS_PB + t * PSTR + 258), 0u);
    }
}

__global__ __launch_bounds__(NTHR, 1) void rbn_fused(
    const float* __restrict__ x, const float* __restrict__ Kp,
    const float* __restrict__ mean_param, const float* __restrict__ var_param,
    float* __restrict__ out, float* __restrict__ ws)
{
    const float c = -Kp[0];
    const float sc = sqrtf(c);
    const float N1 = 1.f / NPTS;
    const int t = threadIdx.x, lane = t & 63, wv = t >> 6;
    const int b = blockIdx.x;
    const int p0 = b * PPB;
    const float4* xr = ((const float4*)x) + p0 * 64;

    float* PA = ws + WS_PA;
    float* PB = ws + WS_PB;

    __shared__ float mu_s[DDIM], om_s[DDIM];
    __shared__ float dpart[PPB * 65];
    __shared__ float dqr[PPB * 9];
    __shared__ float y2_s[PPB], e_s[PPB], d_s[PPB], w_s[PPB], sA_s[PPB], fx_s[PPB];
    __shared__ float pseg[NWAVE * DDIM];
    __shared__ float part1[NWAVE], part2[NWAVE], part3[NWAVE];

    unsigned barno = 0;

    // ---- register-resident x chunk ----
    float4 xreg[PPW];
    #pragma unroll
    for (int i = 0; i < PPW; ++i)
        xreg[i] = xr[(wv * PPW + i) * 64 + lane];

    auto poll_tags = [&](const float* buf) {
        if (t < NBLK) {
            const unsigned* tg = (const unsigned*)(buf + t * PSTR + 258);
            while (ld_u_sc1(tg) < barno)
                __builtin_amdgcn_s_sleep(1);
        }
        __syncthreads();
    };

    // ---- om = exp0(mean_param) ----
    {
        float u = (t < DDIM) ? mean_param[t] : 0.f;
        float un2 = block_sum(u * u);
        float un = sqrtf(fmaxf(un2, EPSF));
        if (t < DDIM) om_s[t] = tanhf(sc * un) * u / (sc * un);
    }
    float om2;
    { float v = (t < DDIM) ? om_s[t] * om_s[t] : 0.f; om2 = block_sum(v); }

    // ================= MEAN PHASE (publish first, dots hidden behind wait) ===
    ++barno;   // = 1
    {
        float4 a = make_float4(0.f, 0.f, 0.f, 0.f);
        #pragma unroll
        for (int i = 0; i < PPW; ++i) {
            a.x += xreg[i].x; a.y += xreg[i].y; a.z += xreg[i].z; a.w += xreg[i].w;
        }
        __syncthreads();                      // M1 (pseg window)
        ((float4*)(pseg + wv * DDIM))[lane] = a;
        __syncthreads();                      // M2
        float s = 0.f;
        if (t < DDIM) {
            #pragma unroll
            for (int w = 0; w < NWAVE; ++w) s += pseg[w * DDIM + t];
        }
        float partner = __shfl_xor(s, 1);
        if (t < DDIM && !(t & 1)) st_pair_sc1(PA + b * PSTR + t, s, partner);
        __syncthreads();                      // M3 drain row stores
        if (t == 0) st_u_sc1((unsigned*)(PA + b * PSTR + 258), barno);
    }
    // hidden work: y2 and e dots
    {
        #pragma unroll
        for (int i = 0; i < PPW; ++i) {
            float4 xv = xreg[i];
            dpart[(wv * PPW + i) * 65 + lane] =
                xv.x * xv.x + xv.y * xv.y + xv.z * xv.z + xv.w * xv.w;
        }
        __syncthreads();                      // M4
        { int pl = t & 127, q = t >> 7; float s = 0.f;
          #pragma unroll
          for (int j = 0; j < 8; ++j) s += dpart[pl * 65 + q * 8 + j];
          dqr[pl * 9 + q] = s; }
        __syncthreads();                      // M5
        if (t < PPB) { float s = 0.f;
            #pragma unroll
            for (int j = 0; j < 8; ++j) s += dqr[t * 9 + j];
            y2_s[t] = s; }
        __syncthreads();                      // M6 (dqr reads done)
        float4 om4 = ((const float4*)om_s)[lane];
        #pragma unroll
        for (int i = 0; i < PPW; ++i) {
            float4 xv = xreg[i];
            dpart[(wv * PPW + i) * 65 + lane] =
                xv.x * om4.x + xv.y * om4.y + xv.z * om4.z + xv.w * om4.w;
        }
        __syncthreads();                      // M7
        { int pl = t & 127, q = t >> 7; float s = 0.f;
          #pragma unroll
          for (int j = 0; j < 8; ++j) s += dpart[pl * 65 + q * 8 + j];
          dqr[pl * 9 + q] = s; }
        __syncthreads();                      // M8
        if (t < PPB) { float s = 0.f;
            #pragma unroll
            for (int j = 0; j < 8; ++j) s += dqr[t * 9 + j];
            e_s[t] = s; }
    }
    poll_tags(PA);                            // M9 inside

    float mu2;
    {
        const int dg = t & 127, sg = t >> 7;
        float ax = 0.f, ay = 0.f;
        #pragma unroll
        for (int j = 0; j < 16; ++j) {
            float2 v = ld_pair_sc1(PA + (sg * 16 + j) * PSTR + 2 * dg);
            ax += v.x; ay += v.y;
        }
        __syncthreads();                      // M10 pseg guard
        ((float2*)(pseg + sg * DDIM))[dg] = make_float2(ax, ay);
        __syncthreads();                      // M11
        float m = 0.f, mm = 0.f;
        if (t < DDIM) {
            float s = 0.f;
            #pragma unroll
            for (int w = 0; w < 8; ++w) s += pseg[w * DDIM + t];
            m = s * N1; mm = m * m;
        }
        #pragma unroll
        for (int off = 32; off; off >>= 1) mm += __shfl_xor(mm, off);
        if (lane == 0) part1[wv] = mm;
        __syncthreads();                      // M12
        float mn2 = 0.f;
        #pragma unroll
        for (int i = 0; i < NWAVE; ++i) mn2 += part1[i];
        float mn = sqrtf(fmaxf(mn2, EPSF));
        float maxn = (1.f - 1e-3f) / sc;
        float f = fminf(1.f, maxn / mn);
        if (t < DDIM) mu_s[t] = m * f;
        mu2 = f * f * mn2;
        __syncthreads();                      // M13 mu_s visible
    }

    // ================= KARCHER ITERATIONS (9 syncs each) =====================
    for (int it = 0; it < FRECHET_ITERS_N; ++it) {
        float* buf = (it & 1) ? PA : PB;
        ++barno;
        float4 mu4 = ((const float4*)mu_s)[lane];
        // A: dot partials
        #pragma unroll
        for (int i = 0; i < PPW; ++i) {
            float4 xv = xreg[i];
            dpart[(wv * PPW + i) * 65 + lane] =
                xv.x * mu4.x + xv.y * mu4.y + xv.z * mu4.z + xv.w * mu4.w;
        }
        __syncthreads();                      // S1
        { int pl = t & 127, q = t >> 7; float s = 0.f;
          #pragma unroll
          for (int j = 0; j < 8; ++j) s += dpart[pl * 65 + q * 8 + j];
          dqr[pl * 9 + q] = s; }
        __syncthreads();                      // S2
        // B2: fused dot finish + scalar chain
        float sAv = 0.f, wdv = 0.f;
        if (t < PPB) {
            float d = 0.f;
            #pragma unroll
            for (int j = 0; j < 8; ++j) d += dqr[t * 9 + j];
            float y2 = y2_s[t];
            float P = 1.f - 2.f * c * d;
            float den = fmaxf(P + c * c * mu2 * y2, EPSF);
            float A = -(P + c * y2) / den;
            float B = (1.f - c * mu2) / den;
            float mn2 = fmaxf(A * A * mu2 + 2.f * A * B * d + B * B * y2, EPSF);
            float mn = sqrtf(mn2);
            float tt = atanhf(fminf(sc * mn, TCLIP));
            float s = (fmaxf(1.f - c * mu2, EPSF) / sc) * tt / mn;
            float w = s * B;
            w_s[t] = w;
            sAv = s * A;
            wdv = w * d;
        }
        __syncthreads();                      // S3 (w_s ready)
        // C: weighted sum + folded scalar butterflies
        {
            float4 a = make_float4(0.f, 0.f, 0.f, 0.f);
            #pragma unroll
            for (int i = 0; i < PPW; ++i) {
                float w = w_s[wv * PPW + i];
                a.x += w * xreg[i].x; a.y += w * xreg[i].y;
                a.z += w * xreg[i].z; a.w += w * xreg[i].w;
            }
            ((float4*)(pseg + wv * DDIM))[lane] = a;
            #pragma unroll
            for (int off = 32; off; off >>= 1) {
                sAv += __shfl_xor(sAv, off); wdv += __shfl_xor(wdv, off);
            }
            if (lane == 0) { part1[wv] = sAv; part2[wv] = wdv; }
        }
        __syncthreads();                      // S4
        // D: column sums + publish
        {
            float s = 0.f;
            if (t < DDIM) {
                #pragma unroll
                for (int w = 0; w < NWAVE; ++w) s += pseg[w * DDIM + t];
            }
            float partner = __shfl_xor(s, 1);
            if (t < DDIM && !(t & 1)) st_pair_sc1(buf + b * PSTR + t, s, partner);
            if (t == 0) {
                float sa = 0.f, wd = 0.f;
                #pragma unroll
                for (int i = 0; i < NWAVE; ++i) { sa += part1[i]; wd += part2[i]; }
                st_pair_sc1(buf + b * PSTR + 256, sa, wd);
            }
        }
        __syncthreads();                      // S5 drain
        if (t == 0) st_u_sc1((unsigned*)(buf + b * PSTR + 258), barno);
        poll_tags(buf);                       // S6 inside
        // E: gather
        const int dg = t & 127, sg = t >> 7;
        float ax = 0.f, ay = 0.f;
        #pragma unroll
        for (int j = 0; j < 16; ++j) {
            float2 v = ld_pair_sc1(buf + (sg * 16 + j) * PSTR + 2 * dg);
            ax += v.x; ay += v.y;
        }
        float2 sp = make_float2(0.f, 0.f);
        if (t < NBLK) sp = ld_pair_sc1(buf + t * PSTR + 256);
        ((float2*)(pseg + sg * DDIM))[dg] = make_float2(ax, ay);
        __syncthreads();                      // S7
        // F: finalize with folded triple reduce
        float g = 0.f, vvv = 0.f;
        if (t < DDIM) {
            #pragma unroll
            for (int w = 0; w < 8; ++w) g += pseg[w * DDIM + t];
            vvv = g * g;
        }
        float sAt = sp.x, wdt = sp.y;
        #pragma unroll
        for (int off = 32; off; off >>= 1) {
            vvv += __shfl_xor(vvv, off); sAt += __shfl_xor(sAt, off); wdt += __shfl_xor(wdt, off);
        }
        if (lane == 0) { part1[wv] = vvv; part2[wv] = sAt; part3[wv] = wdt; }
        __syncthreads();                      // S8
        float vv = 0.f, sa = 0.f, wd = 0.f;
        #pragma unroll
        for (int i = 0; i < NWAVE; ++i) { vv += part1[i]; sa += part2[i]; wd += part3[i]; }
        float gn2 = N1 * N1 * (vv + 2.f * sa * wd + sa * sa * mu2);
        float mg  = N1 * (wd + sa * mu2);
        float un = sqrtf(fmaxf(gn2, EPSF));
        float lam = 2.f / fmaxf(1.f - c * mu2, EPSF);
        float k = tanhf(sc * lam * un * 0.5f) / (sc * un);
        float ms = k * mg;
        float s2 = k * k * gn2;
        float aa = 1.f + 2.f * c * ms + c * s2;
        float bb2 = 1.f - c * mu2;
        float den = fmaxf(1.f + 2.f * c * ms + c * c * mu2 * s2, EPSF);
        float cm = (aa + bb2 * k * N1 * sa) / den;
        float cv = (bb2 * k * N1) / den;
        if (t < DDIM) mu_s[t] = cm * mu_s[t] + cv * g;
        mu2 = cm * cm * mu2 + 2.f * cm * cv * wd + cv * cv * vv;
        __syncthreads();                      // S9 mu_s visible
    }

    // ================= VARIANCE + OUTPUT =====================================
    float* vbuf = ((FRECHET_ITERS_N - 1) & 1) ? PB : PA;
    ++barno;
    {
        float4 mu4 = ((const float4*)mu_s)[lane];
        #pragma unroll
        for (int i = 0; i < PPW; ++i) {
            float4 xv = xreg[i];
            dpart[(wv * PPW + i) * 65 + lane] =
                xv.x * mu4.x + xv.y * mu4.y + xv.z * mu4.z + xv.w * mu4.w;
        }
        __syncthreads();                      // V1
        { int pl = t & 127, q = t >> 7; float s = 0.f;
          #pragma unroll
          for (int j = 0; j < 8; ++j) s += dpart[pl * 65 + q * 8 + j];
          dqr[pl * 9 + q] = s; }
        __syncthreads();                      // V2
        float vval = 0.f;
        if (t < PPB) {
            float d = 0.f;
            #pragma unroll
            for (int j = 0; j < 8; ++j) d += dqr[t * 9 + j];
            d_s[t] = d;
            float y2 = y2_s[t];
            float P = 1.f - 2.f * c * d;
            float den = fmaxf(P + c * c * mu2 * y2, EPSF);
            float A = -(P + c * y2) / den;
            float B = (1.f - c * mu2) / den;
            float mn2 = fmaxf(A * A * mu2 + 2.f * A * B * d + B * B * y2, EPSF);
            float mn = sqrtf(mn2);
            float tt = atanhf(fminf(sc * mn, TCLIP));
            float dd = (2.f / sc) * tt;
            vval = dd * dd;
        }
        // folded: var partial + omu butterflies in one window
        float ov = (t < DDIM) ? om_s[t] * mu_s[t] : 0.f;
        #pragma unroll
        for (int off = 32; off; off >>= 1) {
            vval += __shfl_xor(vval, off); ov += __shfl_xor(ov, off);
        }
        if (lane == 0) { part1[wv] = vval; part2[wv] = ov; }
        __syncthreads();                      // V3
        if (t == 0) {
            float tot = 0.f;
            #pragma unroll
            for (int i = 0; i < NWAVE; ++i) tot += part1[i];
            st_f_sc1(vbuf + b * PSTR + 256, tot);
        }
        __syncthreads();                      // V4 drain
        if (t == 0) st_u_sc1((unsigned*)(vbuf + b * PSTR + 258), barno);
    }
    float omu = 0.f;
    #pragma unroll
    for (int i = 0; i < NWAVE; ++i) omu += part2[i];

    const float Amu = fmaxf(1.f - c * mu2, EPSF);
    const float Aom = fmaxf(1.f - c * om2, EPSF);
    const float ratio = Aom / Amu;
    const float aq = 1.f - 2.f * c * omu + c * mu2;
    const float bq = 1.f - c * om2;
    const float dqv = fmaxf(1.f - 2.f * c * omu + c * c * om2 * mu2, EPSF);
    const float qo = aq / dqv, qm = -bq / dqv;
    const float q2 = qo * qo * om2 + 2.f * qo * qm * omu + qm * qm * mu2;
    const float lam_om = 2.f / Aom;

    // hidden work: gamma-independent output stages (u -> h1 -> h2 -> g2)
    if (t < PPB) {
        float y2 = y2_s[t], d = d_s[t], e = e_s[t];
        auto dotOm3 = [&](float po, float pm, float px) { return po * om2 + pm * omu + px * e; };
        auto dotMu3 = [&](float po, float pm, float px) { return po * omu + pm * mu2 + px * d; };
        auto sqn3 = [&](float po, float pm, float px) {
            return po * po * om2 + pm * pm * mu2 + px * px * y2
                 + 2.f * (po * pm * omu + po * px * e + pm * px * d);
        };
        float P = 1.f - 2.f * c * d;
        float den0 = fmaxf(P + c * c * mu2 * y2, EPSF);
        float A = -(P + c * y2) / den0;
        float B = (1.f - c * mu2) / den0;
        float mn2 = fmaxf(A * A * mu2 + 2.f * A * B * d + B * B * y2, EPSF);
        float mn = sqrtf(mn2);
        float tt = atanhf(fminf(sc * mn, TCLIP));
        float s = (fmaxf(1.f - c * mu2, EPSF) / sc) * tt / mn;
        float Um = s * A, Ux = s * B;

        float xy1 = -dotMu3(0.f, Um, Ux);
        float Y21 = sqn3(0.f, Um, Ux);
        float a1 = 1.f + 2.f * c * xy1 + c * Y21;
        float b1 = 1.f - c * mu2;
        float dn1 = fmaxf(1.f + 2.f * c * xy1 + c * c * mu2 * Y21, EPSF);
        float h1m = (-a1 + b1 * Um) / dn1;
        float h1x = (b1 * Ux) / dn1;

        float xy2 = dotOm3(0.f, h1m, h1x);
        float Y22 = sqn3(0.f, h1m, h1x);
        float a2 = 1.f + 2.f * c * xy2 + c * Y22;
        float b2 = 1.f - c * om2;
        float dn2 = fmaxf(1.f + 2.f * c * xy2 + c * c * om2 * Y22, EPSF);
        float h2o = a2 / dn2;
        float h2m = (b2 * h1m) / dn2;
        float h2x = (b2 * h1x) / dn2;

        float xy3 = -(qo * dotOm3(h2o, h2m, h2x) + qm * dotMu3(h2o, h2m, h2x));
        float Y23 = sqn3(h2o, h2m, h2x);
        float a3 = 1.f + 2.f * c * xy3 + c * Y23;
        float b3 = 1.f - c * q2;
        float dn3 = fmaxf(1.f + 2.f * c * xy3 + c * c * q2 * Y23, EPSF);
        w_s[t]  = (-a3 * qo + b3 * h2o) / dn3;   // g2o
        sA_s[t] = (-a3 * qm + b3 * h2m) / dn3;   // g2m
        fx_s[t] = (b3 * h2x) / dn3;              // g2x
    }
    poll_tags(vbuf);                          // V5 inside

    // var reduce (scalar)
    float va = (t < NBLK) ? ld_f_sc1(vbuf + t * PSTR + 256) : 0.f;
    #pragma unroll
    for (int off = 32; off; off >>= 1) va += __shfl_xor(va, off);
    if (lane == 0) part1[wv] = va;
    __syncthreads();                          // V6
    float vsum = 0.f;
    #pragma unroll
    for (int i = 0; i < NWAVE; ++i) vsum += part1[i];
    float var = vsum * N1;
    float gamma = sqrtf(var_param[0] / (var + 1e-6f));

    // gamma-dependent tail
    if (t < PPB) {
        float y2 = y2_s[t], d = d_s[t], e = e_s[t];
        float g2o = w_s[t], g2m = sA_s[t], g2x = fx_s[t];
        float k1 = ratio * gamma;
        float Lo = k1 * g2o, Lm = k1 * g2m, Lx = k1 * g2x;
        float un2 = Lo * Lo * om2 + Lm * Lm * mu2 + Lx * Lx * y2
                  + 2.f * (Lo * Lm * omu + Lo * Lx * e + Lm * Lx * d);
        float un = sqrtf(fmaxf(un2, EPSF));
        float coef = tanhf(sc * lam_om * un * 0.5f) / (sc * un);
        float So = coef * Lo, Sm = coef * Lm, Sx = coef * Lx;
        float xy4 = So * om2 + Sm * omu + Sx * e;
        float Y24 = coef * coef * un2;
        float a4 = 1.f + 2.f * c * xy4 + c * Y24;
        float b4 = 1.f - c * om2;
        float dn4 = fmaxf(1.f + 2.f * c * xy4 + c * c * om2 * Y24, EPSF);
        w_s[t]  = (a4 + b4 * So) / dn4;   // fo
        sA_s[t] = (b4 * Sm) / dn4;        // fm
        fx_s[t] = (b4 * Sx) / dn4;        // fx
    }
    __syncthreads();                          // V7

    // output store from registers
    {
        float4 mu4f = ((const float4*)mu_s)[lane];
        float4 om4f = ((const float4*)om_s)[lane];
        #pragma unroll
        for (int i = 0; i < PPW; ++i) {
            int pl = wv * PPW + i;
            float fo = w_s[pl], fm = sA_s[pl], fx = fx_s[pl];
            float4 x4 = xreg[i];
            float4 o4;
            o4.x = fo * om4f.x + fm * mu4f.x + fx * x4.x;
            o4.y = fo * om4f.y + fm * mu4f.y + fx * x4.y;
            o4.z = fo * om4f.z + fm * mu4f.z + fx * x4.z;
            o4.w = fo * om4f.w + fm * mu4f.w + fx * x4.w;
            ((float4*)out)[(p0 + pl) * 64 + lane] = o4;
        }
    }
}

extern "C" void kernel_launch(void* const* d_in, const int* in_sizes, int n_in,
                              void* d_out, int out_size, void* d_ws, size_t ws_size,
                              hipStream_t stream) {
    const float* x = (const float*)d_in[0];
    const float* K = (const float*)d_in[1];
    const float* mean_param = (const float*)d_in[2];
    const float* var_param = (const float*)d_in[3];
    float* out = (float*)d_out;
    float* ws = (float*)d_ws;

    init_tags<<<1, 256, 0, stream>>>(ws);
    void* args[] = {(void*)&x, (void*)&K, (void*)&mean_param, (void*)&var_param,
                    (void*)&out, (void*)&ws};
    hipLaunchCooperativeKernel((const void*)rbn_fused, dim3(NBLK), dim3(NTHR),
                               args, 0, stream);
}